// Round 12
// baseline (1318.607 us; speedup 1.0000x reference)
//
#include <hip/hip_runtime.h>

typedef _Float16 half8 __attribute__((ext_vector_type(8)));
typedef _Float16 f16x2 __attribute__((ext_vector_type(2)));
typedef _Float16 f16x4 __attribute__((ext_vector_type(4)));
typedef float floatx4 __attribute__((ext_vector_type(4)));

#define NB 256    // batch
#define NT 512    // time
#define NI 64     // input
#define NH 256    // hidden
#define NSEQ 16   // sequences per group
#define QB 4      // hidden quarters (blocks per group)
#define NGRP (NB / NSEQ)     // 16 groups
#define NBLK (NGRP * QB)     // 64 blocks, 1 CU each
#define THR 256              // 4 waves
#define HS 344               // H row stride in f16 (validated bank pattern)

// B-fragment pack (VALIDATED R9/R10): 480 frags x 64 lanes x 8 f16.
// Cols: [0,256)=r, [256,512)=z, [512,768)=h_n, [768,1024)=i_n. K: [0,256)=h, [256,320)=x.
// frag f: r: tt*10+kb; z: 160+tt*10+kb; h_n: 320+tt*8+kb (kb<8); i_n: 448+tt*2+(kb-8).
// wb[f*512 + lane*8 + i] = W[k = kb*32 + (lane>>4)*8 + i][n = tt*16 + (lane&15)]
#define WB_N (480 * 512)
#define HD_N ((size_t)NT * NB * NH)
#define HX_N ((size_t)2 * NB * NH)   // parity-double-buffered h exchange (f16)

__global__ __launch_bounds__(256) void gru_prep_kernel(
    const float* __restrict__ w_ih, const float* __restrict__ w_hh,
    _Float16* __restrict__ wb, int* __restrict__ flags)
{
  if (blockIdx.x == 0 && threadIdx.x < NBLK) flags[threadIdx.x * 32] = 0;  // reset (padded)
  int n = blockIdx.x * 256 + threadIdx.x;
  if (n >= WB_N) return;
  int i = n & 7, l = (n >> 3) & 63, f = n >> 9;
  int q = l >> 4, col = l & 15;
  int tt, kb, gate;
  if (f < 160)      { tt = f / 10;               kb = f % 10;        gate = 0; }
  else if (f < 320) { int f2 = f - 160; tt = f2 / 10; kb = f2 % 10;  gate = 1; }
  else if (f < 448) { int f3 = f - 320; tt = f3 / 8;  kb = f3 % 8;   gate = 2; }
  else              { int f4 = f - 448; tt = f4 / 2;  kb = 8 + (f4 & 1); gate = 3; }
  int j = (tt & 15) * 16 + col;
  int k = kb * 32 + q * 8 + i;
  float v;
  if (gate == 0)      v = (k < 256) ? w_hh[(0   + j) * 256 + k] : w_ih[(0   + j) * 64 + (k - 256)];
  else if (gate == 1) v = (k < 256) ? w_hh[(256 + j) * 256 + k] : w_ih[(256 + j) * 64 + (k - 256)];
  else if (gate == 2) v = w_hh[(512 + j) * 256 + k];
  else                v = w_ih[(512 + j) * 64 + (k - 256)];
  wb[n] = (_Float16)v;
}

__device__ __forceinline__ float sigm(float v) {
  return __builtin_amdgcn_rcpf(1.0f + __expf(-v));
}
__device__ __forceinline__ float tanh_f(float v) {
  return 1.0f - 2.0f * __builtin_amdgcn_rcpf(1.0f + __expf(2.0f * v));
}

#define MFMA16(a, b, c) __builtin_amdgcn_mfma_f32_16x16x32_f16(a, b, c, 0, 0, 0)
#define FDOT(W, X, A) __builtin_amdgcn_fdot2(__builtin_bit_cast(f16x2, W), \
                                             __builtin_bit_cast(f16x2, X), A, false)

// Relaxed agent-scope atomics: sc1-flagged, device coherence point (L3-served),
// zero cache-maintenance instructions emitted.
typedef unsigned long long u64;
__device__ __forceinline__ u64 hx_load8(const u64* p) {
  return __hip_atomic_load(p, __ATOMIC_RELAXED, __HIP_MEMORY_SCOPE_AGENT);
}
__device__ __forceinline__ void hx_store2(unsigned short* p, unsigned short v) {
  __hip_atomic_store(p, v, __ATOMIC_RELAXED, __HIP_MEMORY_SCOPE_AGENT);
}

// ------------- R22: R21's hidden-split, compressed exchange chain -------------
// R21 measured: per-step 5360 cyc = GEMM ~2000 + GATE ~100 + EXPOSED EXCHANGE
// ~3100 (copy-out bounce 150 + vmcnt 600 + 2 bars + RMW-poll w/ s_sleep 1000-1400
// + gather 700 + writes). R22 compresses the chain, math untouched:
//  1. HX stores fold into GATE (regs -> 4x u16 sc1 atomic store); copy-out +
//     one barrier deleted.
//  2. flag post = relaxed atomic STORE (single writer, monotone) - no RMW RTT.
//  3. poll = relaxed atomic LOAD, tight spin - no RMW, no s_sleep overshoot.
//  4. per-wave partner pipelines: wave p(1-3) polls partner (qb+p)&3 then
//     gathers it immediately (3 partner latencies overlap); wave 0 does
//     x(t+1) prefetch + HD dump concurrently.
//  5. barriers/step 5 -> 2.
// Predicted chain ~2100 cyc -> per-step ~4300 -> ~900 us.
__global__ __launch_bounds__(THR) void gru_kernel(
    const float* __restrict__ x,      // [B, T, I]
    const float* __restrict__ b_ih,   // [768]
    const float* __restrict__ b_hh,   // [768]
    const _Float16* __restrict__ wb,  // packed B fragments
    _Float16* __restrict__ HD,        // [NT][NB][NH] f16 hidden-state dump
    _Float16* __restrict__ HX,        // [2][NB][NH] f16 h exchange (parity)
    int* __restrict__ flags)          // [NBLK*32] monotone step flags (padded)
{
  __shared__ __align__(16) _Float16 H[2][NSEQ][HS];   // 22016 B, double-buffered
  __shared__ __align__(16) _Float16 WB[120 * 512];    // 122880 B: this block's B-slice

  const int tid  = threadIdx.x;     // 0..255
  const int lane = tid & 63;
  const int w    = tid >> 6;        // wave 0..3
  const int q    = lane >> 4;       // quad 0..3
  const int col  = lane & 15;
  const int gidx = blockIdx.x & 15; // group 0..15  (same-XCD partner mapping)
  const int qb   = blockIdx.x >> 4; // hidden quarter 0..3
  const int b0   = gidx * NSEQ;
  const int tt   = qb * 4 + w;      // global col-tile owned by this wave
  const int j    = tt * 16 + col;   // global hidden unit owned in epilogue

  // ---- stage this block's 120 B-frags to LDS (coalesced float4; validated R19) ----
  {
    const float4* src4 = (const float4*)wb;
    float4* dst4 = (float4*)WB;
    #pragma unroll
    for (int it = 0; it < 30; ++it) {
      int d = tid + it * THR;           // 0..7679
      int slot = d >> 6, elem = d & 63;
      int tau = slot / 30, r = slot % 30;
      int gt = qb * 4 + tau;
      int f = (r < 10) ? (gt * 10 + r)
            : (r < 20) ? (160 + gt * 10 + (r - 10))
            : (r < 28) ? (320 + gt * 8 + (r - 20))
                       : (448 + gt * 2 + (r - 28));
      dst4[d] = src4[(size_t)f * 64 + elem];
    }
  }
  const _Float16* wB = WB + (size_t)(w * 30) * 512 + (size_t)lane * 8;

  const float br   = b_ih[j] + b_hh[j];
  const float bz   = b_ih[256 + j] + b_hh[256 + j];
  const float bin_ = b_ih[512 + j];
  const float bhn  = b_hh[512 + j];

  // ---- init: zero H (both buffers), stage x(t=0) ----
  {
    float4* hz = (float4*)H;
    #pragma unroll
    for (int it = 0; it < 6; ++it) {
      int idx = tid + it * THR;
      if (idx < (int)(sizeof(H) / 16)) hz[idx] = float4{0, 0, 0, 0};
    }
  }
  const int r16 = tid >> 4, c4 = (tid & 15) * 4;
  __syncthreads();
  {
    float4 v = *(const float4*)(x + (size_t)(b0 + r16) * (NT * NI) + c4);   // x at t=0
    f16x4 xh; xh[0] = (_Float16)v.x; xh[1] = (_Float16)v.y;
    xh[2] = (_Float16)v.z; xh[3] = (_Float16)v.w;
    *(f16x4*)&H[0][r16][256 + c4] = xh;
  }
  float h0 = 0.0f, h1 = 0.0f, h2 = 0.0f, h3 = 0.0f;
  __syncthreads();

  for (int t = 0; t < NT; ++t) {
    const int cur = t & 1, nxt = cur ^ 1;   // cur = HX parity for h_t

    // ---- GEMM: A row = seq = col (validated), 30 MFMAs/wave ----
    const _Float16* hrow = &H[cur][col][q * 8];
    floatx4 cR = {0,0,0,0}, cZ = {0,0,0,0}, cN = {0,0,0,0}, cI = {0,0,0,0};
    #pragma unroll
    for (int k = 0; k < 8; ++k) {
      half8 a = *(const half8*)(hrow + k * 32);
      cR = MFMA16(a, *(const half8*)(wB + (size_t)(k)      * 512), cR);
      cZ = MFMA16(a, *(const half8*)(wB + (size_t)(10 + k) * 512), cZ);
      cN = MFMA16(a, *(const half8*)(wB + (size_t)(20 + k) * 512), cN);
    }
    { half8 a = *(const half8*)(hrow + 8 * 32);   // x cols [0,32)
      cR = MFMA16(a, *(const half8*)(wB + (size_t)8  * 512), cR);
      cZ = MFMA16(a, *(const half8*)(wB + (size_t)18 * 512), cZ);
      cI = MFMA16(a, *(const half8*)(wB + (size_t)28 * 512), cI); }
    { half8 a = *(const half8*)(hrow + 9 * 32);   // x cols [32,64)
      cR = MFMA16(a, *(const half8*)(wB + (size_t)9  * 512), cR);
      cZ = MFMA16(a, *(const half8*)(wB + (size_t)19 * 512), cZ);
      cI = MFMA16(a, *(const half8*)(wB + (size_t)29 * 512), cI); }

    const bool exch = (t + 1 < NT);

    // ---- GATE -> H[nxt] own cols (LDS) + HX sc1 stores straight from regs ----
#define GATE(m, hvar) { \
    float rr = sigm(cR[m] + br); \
    float zz = sigm(cZ[m] + bz); \
    float nn = tanh_f(cI[m] + bin_ + rr * (cN[m] + bhn)); \
    hvar = (1.0f - zz) * nn + zz * hvar; \
    _Float16 hf = (_Float16)hvar; \
    H[nxt][q * 4 + (m)][j] = hf; \
    if (exch) hx_store2((unsigned short*)(HX + ((size_t)cur * NB + b0 + q * 4 + (m)) * NH + j), \
                        __builtin_bit_cast(unsigned short, hf)); }
    GATE(0, h0) GATE(1, h1) GATE(2, h2) GATE(3, h3)
#undef GATE

    if (exch) {
      // ---- release: own stores acked at coherence point, then post flag ----
      asm volatile("s_waitcnt vmcnt(0)" ::: "memory");
      __syncthreads();                      // barrier 1: all waves' stores acked
      if (tid == 0)
        __hip_atomic_store(&flags[(gidx * QB + qb) * 32], t + 1,
                           __ATOMIC_RELAXED, __HIP_MEMORY_SCOPE_AGENT);

      if (w == 0) {
        // ---- wave 0: x(t+1) prefetch + HD dump of h_{t-1} (overlap window) ----
        float4 xq0, xq1, xq2, xq3;
#define XL(e, dst) { int el = lane + (e) * 64; int row = el >> 4, c4i = (el & 15) * 4; \
        dst = *(const float4*)(x + (size_t)(b0 + row) * (NT * NI) + (size_t)(t + 1) * NI + c4i); }
        XL(0, xq0) XL(1, xq1) XL(2, xq2) XL(3, xq3)
#undef XL
        if (t > 0) {
          #pragma unroll
          for (int e = 0; e < 2; ++e) {
            int el = lane + e * 64;
            int row = el >> 3, c8 = el & 7;
            float4 hv = *(const float4*)&H[cur][row][qb * 64 + c8 * 8];
            *(float4*)(HD + ((size_t)(t - 1) * NB + b0 + row) * NH + qb * 64 + c8 * 8) = hv;
          }
        }
#define XW(e, src) { int el = lane + (e) * 64; int row = el >> 4, c4i = (el & 15) * 4; \
        f16x4 xh; xh[0] = (_Float16)src.x; xh[1] = (_Float16)src.y; \
        xh[2] = (_Float16)src.z; xh[3] = (_Float16)src.w; \
        *(f16x4*)&H[nxt][row][256 + c4i] = xh; }
        XW(0, xq0) XW(1, xq1) XW(2, xq2) XW(3, xq3)
#undef XW
      } else {
        // ---- waves 1-3: poll own partner (tight relaxed-load spin), gather it ----
        const int pw = (qb + w) & 3;       // partner quarter
        const int* fp = &flags[(gidx * QB + pw) * 32];
        while (__hip_atomic_load(fp, __ATOMIC_RELAXED, __HIP_MEMORY_SCOPE_AGENT) < t + 1) {}
        const u64* hxb = (const u64*)(HX + (size_t)cur * NB * NH);
        int u0 = lane, u1 = lane + 64, u2 = lane + 128, u3 = lane + 192;
        u64 v0 = hx_load8(hxb + (size_t)(b0 + (u0 >> 4)) * (NH / 4) + pw * 16 + (u0 & 15));
        u64 v1 = hx_load8(hxb + (size_t)(b0 + (u1 >> 4)) * (NH / 4) + pw * 16 + (u1 & 15));
        u64 v2 = hx_load8(hxb + (size_t)(b0 + (u2 >> 4)) * (NH / 4) + pw * 16 + (u2 & 15));
        u64 v3 = hx_load8(hxb + (size_t)(b0 + (u3 >> 4)) * (NH / 4) + pw * 16 + (u3 & 15));
        *(u64*)&H[nxt][u0 >> 4][pw * 64 + (u0 & 15) * 4] = v0;
        *(u64*)&H[nxt][u1 >> 4][pw * 64 + (u1 & 15) * 4] = v1;
        *(u64*)&H[nxt][u2 >> 4][pw * 64 + (u2 & 15) * 4] = v2;
        *(u64*)&H[nxt][u3 >> 4][pw * 64 + (u3 & 15) * 4] = v3;
      }
      __syncthreads();                      // barrier 2: H[nxt] complete
    } else {
      // last step: dump h_{NT-2}; h_{NT-1} handled after loop
      if (tid < 128) {
        int row = tid >> 3, c8 = tid & 7;
        float4 hv = *(const float4*)&H[cur][row][qb * 64 + c8 * 8];
        *(float4*)(HD + ((size_t)(t - 1) * NB + b0 + row) * NH + qb * 64 + c8 * 8) = hv;
      }
      __syncthreads();                      // H[0] (GATE writes) visible for final dump
    }
  }

  // ---- final dump: h_{NT-1} lives in H[0] (NT even), own 64 cols ----
  if (tid < 128) {
    int row = tid >> 3, c8 = tid & 7;
    float4 hv = *(const float4*)&H[0][row][qb * 64 + c8 * 8];
    *(float4*)(HD + ((size_t)(NT - 1) * NB + b0 + row) * NH + qb * 64 + c8 * 8) = hv;
  }
}

// ---------------- epilogue: out[t][b] = HD[t][b][:] . w_out + b_out ----------------
__global__ __launch_bounds__(256) void gru_out_kernel(
    const _Float16* __restrict__ HD, const float* __restrict__ w_out,
    const float* __restrict__ b_out, float* __restrict__ out)
{
  __shared__ __align__(16) _Float16 WL[NH];
  int tid = threadIdx.x;
  WL[tid] = (_Float16)w_out[tid];
  __syncthreads();
  int gid = blockIdx.x * 256 + tid;          // gid = t*NB + b
  const float4* hp = (const float4*)(HD + (size_t)gid * NH);
  const float4* wp = (const float4*)WL;
  float acc = 0.0f;
  #pragma unroll
  for (int i = 0; i < NH / 8; ++i) {
    float4 hv = hp[i];
    float4 wv = wp[i];
    acc = FDOT(hv.x, wv.x, acc);
    acc = FDOT(hv.y, wv.y, acc);
    acc = FDOT(hv.z, wv.z, acc);
    acc = FDOT(hv.w, wv.w, acc);
  }
  out[gid] = acc + b_out[0];
}

extern "C" void kernel_launch(void* const* d_in, const int* in_sizes, int n_in,
                              void* d_out, int out_size, void* d_ws, size_t ws_size,
                              hipStream_t stream) {
  const float* x     = (const float*)d_in[0];
  const float* w_ih  = (const float*)d_in[1];
  const float* w_hh  = (const float*)d_in[2];
  const float* b_ih  = (const float*)d_in[3];
  const float* b_hh  = (const float*)d_in[4];
  const float* w_out = (const float*)d_in[5];
  const float* b_out = (const float*)d_in[6];
  float* out = (float*)d_out;

  _Float16* wb = (_Float16*)d_ws;            // 480 KB packed B fragments
  _Float16* HD = wb + WB_N;                  // 64 MB hidden-state dump
  _Float16* HX = HD + HD_N;                  // 256 KB h exchange (parity-buffered)
  int* flags   = (int*)(HX + HX_N);          // 8 KB padded monotone flags

  gru_prep_kernel<<<(WB_N + 255) / 256, 256, 0, stream>>>(w_ih, w_hh, wb, flags);
  gru_kernel<<<NBLK, THR, 0, stream>>>(x, b_ih, b_hh, wb, HD, HX, flags);
  gru_out_kernel<<<(NT * NB) / 256, 256, 0, stream>>>(HD, w_out, b_out, out);
}